// Round 12
// baseline (856.434 us; speedup 1.0000x reference)
//
#include <hip/hip_runtime.h>
#include <math.h>

#define NB       8
#define SEQ      8192
#define L1OUT    2048
#define LOUT     1024
#define DMODEL   256
#define DINNER   1024
#define NHEADS   16
#define HEADDIM  64
#define DSTATE   64
#define CONVDIM  1152
#define DINPROJ  2192
#define NPADIN   2304     // in_proj rows padded to multiple of 128
#define NLAYERS  8
#define NCHUNK   16
#define Q        64       // chunk length

#define N_CAST1 (NLAYERS * NPADIN * DMODEL)
#define N_CAST2 (NLAYERS * DMODEL * DINNER)
#define N_CAST3 (DMODEL * 1024)

typedef _Float16 f16;
typedef __attribute__((ext_vector_type(8))) _Float16 f16x8;
typedef __attribute__((ext_vector_type(4))) _Float16 f16x4;
typedef __attribute__((ext_vector_type(4))) float    f32x4;

__device__ __forceinline__ float gelu_f(float v) {
    return 0.5f * v * (1.0f + erff(v * 0.70710678118654752f));
}
__device__ __forceinline__ float silu_f(float v) {
    return v * __builtin_amdgcn_rcpf(1.0f + __expf(-v));
}

__device__ __forceinline__ void gload16(const void* g, void* l) {
    __builtin_amdgcn_global_load_lds(
        (const __attribute__((address_space(1))) unsigned int*)g,
        (__attribute__((address_space(3))) unsigned int*)l, 16, 0, 0);
}

// XCD-chunked swizzle: nblk % 8 == 0. Each XCD gets a contiguous logical
// range (row-major), so same-row/-weight blocks share one XCD's L2.
__device__ __forceinline__ int xcd_chunk(int flat, int nblk) {
    return (flat & 7) * (nblk >> 3) + (flat >> 3);
}

// ------------- all weight casts in one kernel ----------------
__global__ __launch_bounds__(256) void k_castall(const float* __restrict__ w_in,
                                                 const float* __restrict__ w_out,
                                                 const float* __restrict__ w_c2,
                                                 f16* __restrict__ o_in,
                                                 f16* __restrict__ o_out,
                                                 f16* __restrict__ o_c2) {
    int idx = blockIdx.x * 256 + threadIdx.x;
    if (idx < N_CAST1) {
        int c = idx & 255;
        int r = (idx >> 8) % NPADIN;
        int l = idx / (NPADIN * 256);
        float v = (r < DINPROJ) ? w_in[((size_t)l * DINPROJ + r) * 256 + c] : 0.f;
        o_in[idx] = (f16)v;
    } else if (idx < N_CAST1 + N_CAST2) {
        int i = idx - N_CAST1;
        o_out[i] = (f16)w_out[i];
    } else if (idx < N_CAST1 + N_CAST2 + N_CAST3) {
        int i = idx - N_CAST1 - N_CAST2;
        o_c2[i] = (f16)w_c2[i];
    }
}

// ------- conv1 (3->64, k16, s4, pad6) + GELU -> f16, 8 outputs/thread -------
__global__ __launch_bounds__(256) void k_conv1(const float* __restrict__ x,
                                               const float* __restrict__ w,
                                               const float* __restrict__ bias,
                                               f16* __restrict__ out) {
    int idx = blockIdx.x * 256 + threadIdx.x;      // NB*64*256 = 131072
    int u  = idx & 255;                            // 8-output group
    int co = (idx >> 8) & 63;
    int b  = idx >> 14;
    int xbase = u * 32 - 8;

    float acc[8];
#pragma unroll
    for (int t = 0; t < 8; ++t) acc[t] = bias[co];

#pragma unroll
    for (int ci = 0; ci < 3; ++ci) {
        const float* xp = x + ((size_t)b * 3 + ci) * SEQ;
        float xb[48];
#pragma unroll
        for (int j = 0; j < 12; ++j) {
            int off = xbase + j * 4;
            float4 v;
            if (off >= 0 && off + 3 < SEQ) {
                v = *(const float4*)&xp[off];
            } else {
                v.x = (off + 0 >= 0 && off + 0 < SEQ) ? xp[off + 0] : 0.f;
                v.y = (off + 1 >= 0 && off + 1 < SEQ) ? xp[off + 1] : 0.f;
                v.z = (off + 2 >= 0 && off + 2 < SEQ) ? xp[off + 2] : 0.f;
                v.w = (off + 3 >= 0 && off + 3 < SEQ) ? xp[off + 3] : 0.f;
            }
            xb[j * 4 + 0] = v.x; xb[j * 4 + 1] = v.y;
            xb[j * 4 + 2] = v.z; xb[j * 4 + 3] = v.w;
        }
        const float* wp = w + (co * 3 + ci) * 16;
        float wv[16];
#pragma unroll
        for (int k = 0; k < 16; ++k) wv[k] = wp[k];
#pragma unroll
        for (int t = 0; t < 8; ++t)
#pragma unroll
            for (int k = 0; k < 16; ++k)
                acc[t] = fmaf(xb[t * 4 + k + 2], wv[k], acc[t]);
    }
    f16x8 o;
#pragma unroll
    for (int t = 0; t < 8; ++t) o[t] = (f16)gelu_f(acc[t]);
    *(f16x8*)&out[((size_t)(b * 64 + co)) * L1OUT + u * 8] = o;
}

// ------- im2col for conv2 (64ch, k16, s2, pad7), vectorized stores ----------
__global__ __launch_bounds__(256) void k_im2col(const f16* __restrict__ h1,
                                                f16* __restrict__ A) {
    int idx = blockIdx.x * 256 + threadIdx.x;      // 8192*128
    int g = idx & 127;
    int row = idx >> 7;
    int t = row & (LOUT - 1);
    int b = row >> 10;
    int ci = g >> 1, k0 = (g & 1) * 8;
    int pos0 = t * 2 + k0 - 7;
    const f16* hp = h1 + ((size_t)(b * 64 + ci)) * L1OUT;
    f16x8 v;
#pragma unroll
    for (int j = 0; j < 8; ++j) {
        int p = pos0 + j;
        v[j] = (p >= 0 && p < L1OUT) ? hp[p] : (f16)0.f;
    }
    *(f16x8*)&A[(size_t)row * 1024 + g * 8] = v;
}

// ---------------- fp16 MFMA GEMM: C[M,N] = A[M,K] * B[Npad,K]^T --------------
// BK=64, XOR-swizzled LDS, XCD-chunked block swizzle.
// EPI 0: plain f16; 1: gelu(v+bias); 2: f16 + dt cols -> dadt.
template<int BM, int EPI>
__global__ __launch_bounds__(256) void k_hgemm(const f16* __restrict__ A,
                                               const f16* __restrict__ Bw,
                                               f16* __restrict__ Ch,
                                               int M, int N, int K,
                                               const float* __restrict__ bias,
                                               const float* __restrict__ dt_bias,
                                               const float* __restrict__ A_log,
                                               float* __restrict__ dadt) {
    constexpr int MI = BM / 32;
    __shared__ f16 As[BM * 64];
    __shared__ f16 Bs[128 * 64];
    int tid  = threadIdx.x;
    int lane = tid & 63, wid = tid >> 6;
    int wm = wid >> 1, wn = wid & 1;

    int nbx = gridDim.x;
    int flat = blockIdx.y * nbx + blockIdx.x;
    int logical = xcd_chunk(flat, nbx * gridDim.y);
    int row0 = (logical / nbx) * BM, col0 = (logical % nbx) * 128;
    int lr = lane & 15, kb = lane >> 4;

    f32x4 acc[MI][4];
#pragma unroll
    for (int mi = 0; mi < MI; ++mi)
#pragma unroll
        for (int ni = 0; ni < 4; ++ni)
            acc[mi][ni] = (f32x4){0.f, 0.f, 0.f, 0.f};

    int sr  = tid >> 3;                         // 0..31 staging row
    int scx = ((tid & 7) ^ (sr & 7)) * 8;       // swizzled col (f16)
    int rsw = (lr & 7) * 8;                     // read-side XOR (f16)

    for (int k0 = 0; k0 < K; k0 += 64) {
        __syncthreads();
#pragma unroll
        for (int is = 0; is < BM / 32; ++is)
            gload16(A + (size_t)(row0 + is * 32 + sr) * K + k0 + scx,
                    &As[is * 2048 + wid * 512]);
#pragma unroll
        for (int is = 0; is < 4; ++is)
            gload16(Bw + (size_t)(col0 + is * 32 + sr) * K + k0 + scx,
                    &Bs[is * 2048 + wid * 512]);
        __syncthreads();

#pragma unroll
        for (int ks = 0; ks < 2; ++ks) {
            int cbase = (ks * 32 + kb * 8) ^ rsw;
            f16x8 a[MI], b[4];
#pragma unroll
            for (int mi = 0; mi < MI; ++mi)
                a[mi] = *reinterpret_cast<const f16x8*>(
                    &As[(wm * (BM / 2) + mi * 16 + lr) * 64 + cbase]);
#pragma unroll
            for (int ni = 0; ni < 4; ++ni)
                b[ni] = *reinterpret_cast<const f16x8*>(
                    &Bs[(wn * 64 + ni * 16 + lr) * 64 + cbase]);
#pragma unroll
            for (int mi = 0; mi < MI; ++mi)
#pragma unroll
                for (int ni = 0; ni < 4; ++ni)
                    acc[mi][ni] = __builtin_amdgcn_mfma_f32_16x16x32_f16(
                        a[mi], b[ni], acc[mi][ni], 0, 0, 0);
        }
    }

#pragma unroll
    for (int mi = 0; mi < MI; ++mi)
#pragma unroll
        for (int ni = 0; ni < 4; ++ni) {
            int ccol = col0 + wn * 64 + ni * 16 + lr;
            if (ccol < N) {
                int rbase = row0 + wm * (BM / 2) + mi * 16 + kb * 4;
                f32x4 v = acc[mi][ni];
#pragma unroll
                for (int r = 0; r < 4; ++r) {
                    float val = v[r];
                    if (EPI == 1) val = gelu_f(val + bias[ccol]);
                    Ch[(size_t)(rbase + r) * N + ccol] = (f16)val;
                    if (EPI == 2 && ccol >= DINNER + CONVDIM) {
                        int hh = ccol - (DINNER + CONVDIM);
                        float raw = val + dt_bias[hh];
                        float dtv = (raw > 20.f) ? raw : log1pf(__expf(raw));
                        float lda = -__expf(A_log[hh]) * dtv;
                        *(float2*)&dadt[(size_t)(rbase + r) * 32 + hh * 2] =
                            make_float2(lda, dtv);
                    }
                }
            }
        }
}

// ---------------- SSD part 1: per (b, chunk, 4 heads) ----------------
// Fused depthwise conv+SiLU staging of B/C/X from zx16; G = C.B^T;
// per head: S = X^T.(w*B)^T (f16), M = masked decay*G (+D on diag),
// Y_intra = M.X -> y1 (f16). hq==0 also writes conv'd C to C16 for ssd2.
__global__ __launch_bounds__(256) void k_ssd1(const f16* __restrict__ zx16,
                                              const float* __restrict__ dadt,
                                              const float* __restrict__ dw_w,
                                              const float* __restrict__ dw_b,
                                              const float* __restrict__ ssmD,
                                              f16* __restrict__ y1,
                                              f16* __restrict__ Sbuf16,
                                              float* __restrict__ Abuf,
                                              f16* __restrict__ C16) {
    __shared__ f16 Bs[64][72];
    __shared__ f16 Cs[64][72];
    __shared__ float GT[64][68];            // GT[s][t]
    __shared__ f16 Mw[4][64][72];           // X staging, then per-wave sBT / M
    __shared__ float2 LaDt[4][64];

    int tid = threadIdx.x, lane = tid & 63, wid = tid >> 6;
    int bid = xcd_chunk(blockIdx.x, NB * NCHUNK * 4);  // hq-blocks colocate
    int hq = bid & 3, c = (bid >> 2) & 15, b = bid >> 6;
    int h = hq * 4 + wid;
    int lr = lane & 15, kb = lane >> 4;
    f16* Xs = &Mw[0][0][0];                 // [64][260] f16 (33,280 B)

    // ---- fused conv+SiLU staging: threads 0..191 own (ch-group, 16-t slice)
    {
        int sg = tid % 48;                  // 0..31 X, 32..39 B, 40..47 C
        int ts = tid / 48;                  // t-slice (use 0..3)
        if (ts < 4) {
            int xc;                         // xbc-channel base (weight index)
            if (sg < 32)      xc = hq * 256 + sg * 8;
            else if (sg < 40) xc = 1024 + (sg - 32) * 8;
            else              xc = 1088 + (sg - 40) * 8;
            int zc = 1024 + xc;             // zx16 column
            float4 wv[8];
            float  bv[8];
#pragma unroll
            for (int j = 0; j < 8; ++j) {
                wv[j] = *(const float4*)&dw_w[(xc + j) * 4];
                bv[j] = dw_b[xc + j];
            }
            int l0 = c * 64 + ts * 16;      // in-batch row of first output
            const f16* zrow = zx16 + ((size_t)(b * 1024 + l0)) * DINPROJ + zc;
            f16x8 r0, r1, r2, r3;
            f16x8 zz;
#pragma unroll
            for (int j = 0; j < 8; ++j) zz[j] = (f16)0.f;
            r0 = (l0 >= 3) ? *(const f16x8*)(zrow - 3 * DINPROJ) : zz;
            r1 = (l0 >= 2) ? *(const f16x8*)(zrow - 2 * DINPROJ) : zz;
            r2 = (l0 >= 1) ? *(const f16x8*)(zrow - 1 * DINPROJ) : zz;
#pragma unroll
            for (int t = 0; t < 16; ++t) {
                r3 = *(const f16x8*)(zrow + t * DINPROJ);
                f16x8 o;
#pragma unroll
                for (int j = 0; j < 8; ++j) {
                    float s = bv[j];
                    s = fmaf((float)r0[j], wv[j].x, s);
                    s = fmaf((float)r1[j], wv[j].y, s);
                    s = fmaf((float)r2[j], wv[j].z, s);
                    s = fmaf((float)r3[j], wv[j].w, s);
                    o[j] = (f16)silu_f(s);
                }
                int row = ts * 16 + t;
                if (sg < 32) {
                    f16x4 o0 = {o[0], o[1], o[2], o[3]};
                    f16x4 o1 = {o[4], o[5], o[6], o[7]};
                    *(f16x4*)&Xs[row * 260 + sg * 8]     = o0;
                    *(f16x4*)&Xs[row * 260 + sg * 8 + 4] = o1;
                } else if (sg < 40) {
                    *(f16x8*)&Bs[row][(sg - 32) * 8] = o;
                } else {
                    *(f16x8*)&Cs[row][(sg - 40) * 8] = o;
                }
                r0 = r1; r1 = r2; r2 = r3;
            }
        }
    }

    // per-lane (lane = t): log-decay cumsum + dt (independent of staging)
    float2 ad = *(const float2*)&dadt[((size_t)(b * 1024 + c * 64 + lane) * 16 + h) * 2];
    float La = ad.x;
#pragma unroll
    for (int o = 1; o < 64; o <<= 1) {
        float v = __shfl_up(La, o);
        if (lane >= o) La += v;
    }
    float dt_own = ad.y;
    float La63 = __shfl(La, 63);
    float w_own = __expf(La63 - La) * dt_own;   // state weight, <= dt
    LaDt[wid][lane] = make_float2(La, dt_own);
    float Dh = ssmD[h];
    __syncthreads();

    // export conv'd C for ssd2 (one hq per (b,c))
    if (hq == 0) {
        f16* cp = C16 + (((size_t)(b * 16 + c)) << 12);
#pragma unroll
        for (int it = 0; it < 2; ++it) {
            int cid = it * 256 + tid;
            int row = cid >> 3, off = (cid & 7) * 8;
            *(f16x8*)&cp[row * 64 + off] = *(const f16x8*)&Cs[row][off];
        }
    }

    // read X^T fragments from LDS (row p, k=t)
    f16x8 xfrag[4][2];
#pragma unroll
    for (int pi = 0; pi < 4; ++pi)
#pragma unroll
        for (int ks = 0; ks < 2; ++ks) {
            f16x8 v;
#pragma unroll
            for (int j = 0; j < 8; ++j)
                v[j] = Xs[(ks * 32 + kb * 8 + j) * 260 + wid * 64 + pi * 16 + lr];
            xfrag[pi][ks] = v;
        }

    // G = C.B^T : each wave one 32x32 quadrant -> GT[s][t]
    {
        int tq = wid & 1, sq = wid >> 1;
        f32x4 g[2][2];
#pragma unroll
        for (int i = 0; i < 2; ++i)
#pragma unroll
            for (int j = 0; j < 2; ++j) g[i][j] = (f32x4){0.f, 0.f, 0.f, 0.f};
#pragma unroll
        for (int ks = 0; ks < 2; ++ks) {
            f16x8 a[2], bb[2];
#pragma unroll
            for (int ti = 0; ti < 2; ++ti)
                a[ti] = *(const f16x8*)&Cs[tq * 32 + ti * 16 + lr][ks * 32 + kb * 8];
#pragma unroll
            for (int si = 0; si < 2; ++si)
                bb[si] = *(const f16x8*)&Bs[sq * 32 + si * 16 + lr][ks * 32 + kb * 8];
#pragma unroll
            for (int ti = 0; ti < 2; ++ti)
#pragma unroll
                for (int si = 0; si < 2; ++si)
                    g[ti][si] = __builtin_amdgcn_mfma_f32_16x16x32_f16(
                        a[ti], bb[si], g[ti][si], 0, 0, 0);
        }
#pragma unroll
        for (int ti = 0; ti < 2; ++ti)
#pragma unroll
            for (int si = 0; si < 2; ++si)
#pragma unroll
                for (int r = 0; r < 4; ++r)
                    GT[sq * 32 + si * 16 + lr][tq * 32 + ti * 16 + kb * 4 + r] = g[ti][si][r];
    }
    __syncthreads();   // GT ready; all xfrag reads done -> Mw reusable

    // ---- head phase (wave-local) ----
    // sBT[n][t] = B[t][n] * w_t  into Mw[wid]
    {
        f16x8 brow[8];
#pragma unroll
        for (int i = 0; i < 8; ++i) brow[i] = *(const f16x8*)&Bs[lane][i * 8];
#pragma unroll
        for (int i = 0; i < 8; ++i)
#pragma unroll
            for (int j = 0; j < 8; ++j)
                Mw[wid][i * 8 + j][lane] = (f16)((float)brow[i][j] * w_own);
    }
    __builtin_amdgcn_wave_barrier();

    f16x8 sbfrag[4][2];
#pragma unroll
    for (int ni = 0; ni < 4; ++ni)
#pragma unroll
        for (int ks = 0; ks < 2; ++ks)
            sbfrag[ni][ks] = *(const f16x8*)&Mw[wid][ni * 16 + lr][ks * 32 + kb * 8];

    // S[p][n] = sum_t X^T[p][t] sBT[n][t]  -> f16
    {
        f32x4 accS[4][4];
#pragma unroll
        for (int pi = 0; pi < 4; ++pi)
#pragma unroll
            for (int ni = 0; ni < 4; ++ni) accS[pi][ni] = (f32x4){0.f, 0.f, 0.f, 0.f};
#pragma unroll
        for (int ks = 0; ks < 2; ++ks)
#pragma unroll
            for (int pi = 0; pi < 4; ++pi)
#pragma unroll
                for (int ni = 0; ni < 4; ++ni)
                    accS[pi][ni] = __builtin_amdgcn_mfma_f32_16x16x32_f16(
                        xfrag[pi][ks], sbfrag[ni][ks], accS[pi][ni], 0, 0, 0);
        size_t sbase = ((size_t)((b * 16 + h) * 16 + c)) << 12;
#pragma unroll
        for (int pi = 0; pi < 4; ++pi)
#pragma unroll
            for (int ni = 0; ni < 4; ++ni)
#pragma unroll
                for (int r = 0; r < 4; ++r)
                    Sbuf16[sbase + (size_t)(pi * 16 + kb * 4 + r) * 64 + ni * 16 + lr] =
                        (f16)accS[pi][ni][r];
        if (lane == 0) Abuf[(b * 16 + h) * 16 + c] = __expf(La63);
    }
    __builtin_amdgcn_wave_barrier();

    // M[t][s] = (s<=t) ? G[t][s]*exp(La_t-La_s)*dt_s : 0 ; M[t][t] += D_h
    {
        int t = lane;
        float la_t = La;
#pragma unroll
        for (int s8 = 0; s8 < 8; ++s8) {
            f16x8 mv;
#pragma unroll
            for (int j = 0; j < 8; ++j) {
                int s = s8 * 8 + j;
                float2 ld = LaDt[wid][s];
                float m = (s <= t) ? GT[s][t] * __expf(la_t - ld.x) * ld.y : 0.f;
                if (s == t) m += Dh;
                mv[j] = (f16)m;
            }
            *(f16x8*)&Mw[wid][t][s8 * 8] = mv;
        }
    }
    __builtin_amdgcn_wave_barrier();

    // Y_intra[t][p] = sum_s M[t][s] X[s][p]  -> f16 (includes D*xh)
    {
        f32x4 accY[4][4];
#pragma unroll
        for (int ti = 0; ti < 4; ++ti)
#pragma unroll
            for (int pi = 0; pi < 4; ++pi) accY[ti][pi] = (f32x4){0.f, 0.f, 0.f, 0.f};
#pragma unroll
        for (int ks = 0; ks < 2; ++ks) {
            f16x8 af[4];
#pragma unroll
            for (int ti = 0; ti < 4; ++ti)
                af[ti] = *(const f16x8*)&Mw[wid][ti * 16 + lr][ks * 32 + kb * 8];
#pragma unroll
            for (int ti = 0; ti < 4; ++ti)
#pragma unroll
                for (int pi = 0; pi < 4; ++pi)
                    accY[ti][pi] = __builtin_amdgcn_mfma_f32_16x16x32_f16(
                        af[ti], xfrag[pi][ks], accY[ti][pi], 0, 0, 0);
        }
        f16* yp = y1 + ((size_t)(b * 1024 + c * 64)) * 1024 + h * 64;
#pragma unroll
        for (int ti = 0; ti < 4; ++ti)
#pragma unroll
            for (int pi = 0; pi < 4; ++pi)
#pragma unroll
                for (int r = 0; r < 4; ++r)
                    yp[(size_t)(ti * 16 + kb * 4 + r) * 1024 + pi * 16 + lr] =
                        (f16)accY[ti][pi][r];
    }
}

// ------- fused inter-chunk recurrence + SSD part 2, 4-way p-split -----------
// Block = (b, h, ph): p-slice [ph*16, ph*16+16). Phase 1: 16-chunk state
// recurrence for 16x64 slice -> swizzled LDS (32 KiB). Phase 2: wave wv
// computes 4 chunks' y2 slice = exp(La)*(C . H^T).
__global__ __launch_bounds__(256) void k_ssd2f(const f16* __restrict__ C16,
                                               const f16* __restrict__ Sbuf16,
                                               const float* __restrict__ Abuf,
                                               const float* __restrict__ dadt,
                                               f16* __restrict__ y2) {
    __shared__ f16 Hs[NCHUNK][1024];      // 32 KiB
    int tid = threadIdx.x, lane = tid & 63, wv = tid >> 6;
    int bid = xcd_chunk(blockIdx.x, NB * NHEADS * 4);   // same-b colocate
    int ph = bid & 3, h = (bid >> 2) & 15, b = bid >> 6;
    int bh = b * 16 + h;
    int lr = lane & 15, kb = lane >> 4;
    size_t base = ((size_t)bh << 16) + ph * 1024;   // p-slice offset in Sbuf

    // phase 1: recurrence for p in [ph*16, ph*16+16), 4 elems/thread
    {
        int lp = tid >> 4;                 // 0..15 local p
        int n0 = (tid & 15) * 4;           // 0..60
        int dst = lp * 64 + ((((n0 >> 3) ^ (lp & 7))) << 3) + (n0 & 7);
        float Hl[4];
#pragma unroll
        for (int j = 0; j < 4; ++j) Hl[j] = 0.f;
#pragma unroll
        for (int c = 0; c < NCHUNK; ++c) {
            f16x4 o;
#pragma unroll
            for (int j = 0; j < 4; ++j) o[j] = (f16)Hl[j];
            *(f16x4*)&Hs[c][dst] = o;
            float A = Abuf[bh * 16 + c];
            f16x4 s = *(const f16x4*)&Sbuf16[base + (size_t)c * 4096 + lp * 64 + n0];
#pragma unroll
            for (int j = 0; j < 4; ++j)
                Hl[j] = fmaf(Hl[j], A, (float)s[j]);
        }
    }
    __syncthreads();

    // phase 2
    const f16* cpb = C16 + ((size_t)b << 16);
#pragma unroll
    for (int i = 0; i < 4; ++i) {
        int c = wv * 4 + i;
        float2 ad = *(const float2*)&dadt[((size_t)(b * 1024 + c * 64 + lane) * 16 + h) * 2];
        float La = ad.x;
#pragma unroll
        for (int o = 1; o < 64; o <<= 1) {
            float v = __shfl_up(La, o);
            if (lane >= o) La += v;
        }

        f16x8 hfrag[2];
#pragma unroll
        for (int ks = 0; ks < 2; ++ks) {
            int cf = (ks * 32 + kb * 8) ^ ((lr & 7) * 8);
            hfrag[ks] = *(const f16x8*)&Hs[c][lr * 64 + cf];
        }

        const f16* cp = cpb + ((size_t)c << 12);
        f32x4 acc[4];
#pragma unroll
        for (int ti = 0; ti < 4; ++ti) acc[ti] = (f32x4){0.f, 0.f, 0.f, 0.f};
#pragma unroll
        for (int ks = 0; ks < 2; ++ks) {
            f16x8 af[4];
#pragma unroll
            for (int ti = 0; ti < 4; ++ti)
                af[ti] = *(const f16x8*)(cp + (ti * 16 + lr) * 64 + ks * 32 + kb * 8);
#pragma unroll
            for (int ti = 0; ti < 4; ++ti)
                acc[ti] = __builtin_amdgcn_mfma_f32_16x16x32_f16(
                    af[ti], hfrag[ks], acc[ti], 0, 0, 0);
        }
        f16* yp = y2 + ((size_t)(b * 1024 + c * 64)) * 1024 + h * 64 + ph * 16;
#pragma unroll
        for (int ti = 0; ti < 4; ++ti)
#pragma unroll
            for (int r = 0; r < 4; ++r) {
                int t = ti * 16 + kb * 4 + r;
                float sc = __expf(__shfl(La, t));
                yp[(size_t)t * 1024 + lr] = (f16)(sc * acc[ti][r]);
            }
    }
}

// ---- y = (y1 + y2) * silu(z); RMSNorm * rms_w; wave-per-row, no LDS --------
__global__ __launch_bounds__(256) void k_gate(const f16* __restrict__ zx16,
                                              const float* __restrict__ rmsw,
                                              const f16* __restrict__ y1,
                                              const f16* __restrict__ y2,
                                              f16* __restrict__ ygate) {
    int tid = threadIdx.x, lane = tid & 63, w = tid >> 6;
    int bl = blockIdx.x * 4 + w;
    int c = lane * 16;
    const f16* p1 = y1 + (size_t)bl * DINNER + c;
    const f16* p2 = y2 + (size_t)bl * DINNER + c;
    const f16* pz = zx16 + (size_t)bl * DINPROJ + c;
    float v[16];
    float ss = 0.f;
#pragma unroll
    for (int hh = 0; hh < 2; ++hh) {
        f16x8 a = *(const f16x8*)(p1 + hh * 8);
        f16x8 b2 = *(const f16x8*)(p2 + hh * 8);
        f16x8 z = *(const f16x8*)(pz + hh * 8);
#pragma unroll
        for (int j = 0; j < 8; ++j) {
            float vv = ((float)a[j] + (float)b2[j]) * silu_f((float)z[j]);
            v[hh * 8 + j] = vv;
            ss += vv * vv;
        }
    }
#pragma unroll
    for (int o = 32; o > 0; o >>= 1) ss += __shfl_xor(ss, o);
    float r = rsqrtf(ss * (1.f / DINNER) + 1e-5f);
#pragma unroll
    for (int hh = 0; hh < 2; ++hh) {
        f16x8 o8;
#pragma unroll
        for (int j = 0; j < 8; ++j)
            o8[j] = (f16)(v[hh * 8 + j] * r * rmsw[c + hh * 8 + j]);
        *(f16x8*)&ygate[(size_t)bl * DINNER + c + hh * 8] = o8;
    }
}

// -- final LayerNorm + mean pool: wave-per-row, per-(b,seg) partial (no atomic)
__global__ __launch_bounds__(256) void k_lnpool(const f16* __restrict__ h,
                                                const float* __restrict__ lnw,
                                                const float* __restrict__ lnb,
                                                float* __restrict__ pooledp) {
    __shared__ float pl[4][256];
    int bid = blockIdx.x;                // 8 * 32
    int b = bid >> 5, seg = bid & 31;
    int tid = threadIdx.x, lane = tid & 63, w = tid >> 6;
    int c4 = lane * 4;
    float4 lw = *(const float4*)&lnw[c4];
    float4 lb = *(const float4*)&lnb[c4];
    float acc0 = 0.f, acc1 = 0.f, acc2 = 0.f, acc3 = 0.f;
    const f16* hb = h + ((size_t)b * 1024 + seg * 32 + w * 8) * DMODEL;
#pragma unroll
    for (int i = 0; i < 8; ++i) {
        f16x4 hv = *(const f16x4*)(hb + (size_t)i * DMODEL + c4);
        float vx = (float)hv.x, vy = (float)hv.y, vz = (float)hv.z, vw = (float)hv.w;
        float s1 = vx + vy + vz + vw;
        float s2 = vx * vx + vy * vy + vz * vz + vw * vw;
#pragma unroll
        for (int o = 32; o > 0; o >>= 1) {
            s1 += __shfl_xor(s1, o);
            s2 += __shfl_xor(s2, o);
        }
        float mu = s1 * (1.f / DMODEL);
        float var = s2 * (1.f / DMODEL) - mu * mu;
        float rr = rsqrtf(var + 1e-5f);
        acc0 += (vx - mu) * rr * lw.x + lb.x;
        acc1 += (vy - mu) * rr * lw.y + lb.y;
        acc2 += (vz - mu) * rr * lw.z + lb.z;
        acc3 += (vw - mu) * rr * lw.w + lb.w;
    }
    pl[w][c4 + 0] = acc0; pl[w][c4 + 1] = acc1;
    pl[w][c4 + 2] = acc2; pl[w][c4 + 3] = acc3;
    __syncthreads();
    float tot = pl[0][tid] + pl[1][tid] + pl[2][tid] + pl[3][tid];
    pooledp[(size_t)(b * 32 + seg) * 256 + tid] = tot;
}

// ---------------- regression head (reduces 32 partials) ----------------
__global__ __launch_bounds__(128) void k_head(const float* __restrict__ pooledp,
                                              const float* __restrict__ w1,
                                              const float* __restrict__ b1,
                                              const float* __restrict__ w2,
                                              const float* __restrict__ b2,
                                              float* __restrict__ out) {
    __shared__ float sp[256];
    __shared__ float red[2];
    int b = blockIdx.x, j = threadIdx.x;
    for (int d = j; d < 256; d += 128) {
        float s = 0.f;
#pragma unroll
        for (int seg = 0; seg < 32; ++seg)
            s += pooledp[(size_t)(b * 32 + seg) * 256 + d];
        sp[d] = s * (1.f / LOUT);
    }
    __syncthreads();
    float acc = b1[j];
#pragma unroll 8
    for (int d = 0; d < DMODEL; ++d)
        acc = fmaf(sp[d], w1[j * DMODEL + d], acc);
    float r = gelu_f(acc) * w2[j];
#pragma unroll
    for (int o = 32; o > 0; o >>= 1) r += __shfl_down(r, o, 64);
    int lane = j & 63, wid = j >> 6;
    if (lane == 0) red[wid] = r;
    __syncthreads();
    if (j == 0) out[b] = red[0] + red[1] + b2[0];
}

extern "C" void kernel_launch(void* const* d_in, const int* in_sizes, int n_in,
                              void* d_out, int out_size, void* d_ws, size_t ws_size,
                              hipStream_t stream) {
    const float* x         = (const float*)d_in[0];
    const float* conv1_w   = (const float*)d_in[1];
    const float* conv1_b   = (const float*)d_in[2];
    const float* conv2_w   = (const float*)d_in[3];
    const float* conv2_b   = (const float*)d_in[4];
    const float* in_proj_w = (const float*)d_in[5];
    const float* dw_w      = (const float*)d_in[6];
    const float* dw_b      = (const float*)d_in[7];
    const float* dt_bias   = (const float*)d_in[8];
    const float* A_log     = (const float*)d_in[9];
    const float* ssm_D     = (const float*)d_in[10];
    const float* rms_w     = (const float*)d_in[11];
    const float* out_proj_w= (const float*)d_in[12];
    const float* ln_w      = (const float*)d_in[13];
    const float* ln_b      = (const float*)d_in[14];
    const float* reg1_w    = (const float*)d_in[15];
    const float* reg1_b    = (const float*)d_in[16];
    const float* reg2_w    = (const float*)d_in[17];
    const float* reg2_b    = (const float*)d_in[18];

    float* ws = (float*)d_ws;
    size_t off = 0;
    float* dadt    = ws + off; off += (size_t)NB * LOUT * NHEADS * 2; // 262,144
    float* Abuf    = ws + off; off += (size_t)NB * NHEADS * NCHUNK;   // 2,048
    float* pooledp = ws + off; off += (size_t)NB * 32 * 256;          // 65,536

    f16* fbase = (f16*)(ws + off);
    size_t foff = 0;
    f16* c1f16  = fbase + foff; foff += (size_t)NB * 64 * L1OUT;
    f16* hbf0   = fbase + foff; foff += (size_t)NB * LOUT * DMODEL;
    f16* hbf1   = fbase + foff; foff += (size_t)NB * LOUT * DMODEL;
    f16* ygate  = fbase + foff; foff += (size_t)NB * LOUT * DINNER;
    f16* y2     = fbase + foff; foff += (size_t)NB * LOUT * DINNER;
    f16* y1     = fbase + foff; foff += (size_t)NB * LOUT * DINNER;   // also im2h
    f16* C16    = fbase + foff; foff += (size_t)NB * NCHUNK * 64 * 64;
    f16* zx16   = fbase + foff; foff += (size_t)NB * LOUT * DINPROJ;
    f16* Sbuf16 = fbase + foff; foff += (size_t)NB * NHEADS * NCHUNK * 4096;
    f16* w_in_h = fbase + foff; foff += (size_t)NLAYERS * NPADIN * DMODEL;
    f16* w_out_h= fbase + foff; foff += (size_t)NLAYERS * DMODEL * DINNER;
    f16* w_c2_h = fbase + foff; foff += (size_t)DMODEL * 1024;
    f16* im2h   = y1;          // aliased: im2col dead before y1 first written

    // all weight casts in one launch
    {
        int total = N_CAST1 + N_CAST2 + N_CAST3;
        k_castall<<<(total + 255) / 256, 256, 0, stream>>>(
            in_proj_w, out_proj_w, conv2_w, w_in_h, w_out_h, w_c2_h);
    }

    // front-end convs
    k_conv1<<<(NB * 64 * 256) / 256, 256, 0, stream>>>(x, conv1_w, conv1_b, c1f16);
    k_im2col<<<(NB * LOUT * 128) / 256, 256, 0, stream>>>(c1f16, im2h);
    {
        dim3 g(256 / 128, 8192 / 64);
        k_hgemm<64, 1><<<g, 256, 0, stream>>>(im2h, w_c2_h, hbf0,
                                              8192, 256, 1024, conv2_b,
                                              nullptr, nullptr, nullptr);
    }

    f16* hcur = hbf0;
    f16* hnxt = hbf1;
    for (int i = 0; i < NLAYERS; ++i) {
        {
            dim3 g(NPADIN / 128, 8192 / 128);
            k_hgemm<128, 2><<<g, 256, 0, stream>>>(
                hcur, w_in_h + (size_t)i * NPADIN * DMODEL, zx16,
                8192, DINPROJ, DMODEL, nullptr,
                dt_bias + i * NHEADS, A_log + i * NHEADS, dadt);
        }
        k_ssd1<<<NB * NCHUNK * 4, 256, 0, stream>>>(
            zx16, dadt, dw_w + (size_t)i * CONVDIM * 4, dw_b + (size_t)i * CONVDIM,
            ssm_D + i * NHEADS, y1, Sbuf16, Abuf, C16);
        k_ssd2f<<<NB * NHEADS * 4, 256, 0, stream>>>(C16, Sbuf16, Abuf, dadt, y2);
        k_gate<<<NB * LOUT / 4, 256, 0, stream>>>(zx16, rms_w + (size_t)i * DINNER,
                                                  y1, y2, ygate);
        {
            dim3 g(DMODEL / 128, 8192 / 64);
            k_hgemm<64, 0><<<g, 256, 0, stream>>>(
                ygate, w_out_h + (size_t)i * DMODEL * DINNER, hnxt,
                8192, DMODEL, DINNER, nullptr, nullptr, nullptr, nullptr);
        }
        f16* tmp = hcur; hcur = hnxt; hnxt = tmp;
    }

    // final LN + pool + head
    k_lnpool<<<NB * 32, 256, 0, stream>>>(hcur, ln_w, ln_b, pooledp);
    k_head<<<NB, 128, 0, stream>>>(pooledp, reg1_w, reg1_b, reg2_w, reg2_b, (float*)d_out);
}

// Round 13
// 838.555 us; speedup vs baseline: 1.0213x; 1.0213x over previous
//
#include <hip/hip_runtime.h>
#include <math.h>

#define NB       8
#define SEQ      8192
#define L1OUT    2048
#define LOUT     1024
#define DMODEL   256
#define DINNER   1024
#define NHEADS   16
#define HEADDIM  64
#define DSTATE   64
#define CONVDIM  1152
#define DINPROJ  2192
#define NPADIN   2304     // in_proj rows padded to multiple of 128
#define NLAYERS  8
#define NCHUNK   16
#define Q        64       // chunk length

#define N_CAST1 (NLAYERS * NPADIN * DMODEL)
#define N_CAST2 (NLAYERS * DMODEL * DINNER)
#define N_CAST3 (DMODEL * 1024)

typedef _Float16 f16;
typedef __attribute__((ext_vector_type(8))) _Float16 f16x8;
typedef __attribute__((ext_vector_type(4))) _Float16 f16x4;
typedef __attribute__((ext_vector_type(4))) float    f32x4;

__device__ __forceinline__ float gelu_f(float v) {
    return 0.5f * v * (1.0f + erff(v * 0.70710678118654752f));
}
__device__ __forceinline__ float silu_f(float v) {
    return v * __builtin_amdgcn_rcpf(1.0f + __expf(-v));
}

__device__ __forceinline__ void gload16(const void* g, void* l) {
    __builtin_amdgcn_global_load_lds(
        (const __attribute__((address_space(1))) unsigned int*)g,
        (__attribute__((address_space(3))) unsigned int*)l, 16, 0, 0);
}

// XCD-chunked swizzle: nblk % 8 == 0. Each XCD gets a contiguous logical
// range (row-major), so same-row/-weight blocks share one XCD's L2.
__device__ __forceinline__ int xcd_chunk(int flat, int nblk) {
    return (flat & 7) * (nblk >> 3) + (flat >> 3);
}

// ------------- all weight casts in one kernel (out_proj × rmsw fold) --------
__global__ __launch_bounds__(256) void k_castall(const float* __restrict__ w_in,
                                                 const float* __restrict__ w_out,
                                                 const float* __restrict__ rmsw,
                                                 const float* __restrict__ w_c2,
                                                 f16* __restrict__ o_in,
                                                 f16* __restrict__ o_out,
                                                 f16* __restrict__ o_c2) {
    int idx = blockIdx.x * 256 + threadIdx.x;
    if (idx < N_CAST1) {
        int c = idx & 255;
        int r = (idx >> 8) % NPADIN;
        int l = idx / (NPADIN * 256);
        float v = (r < DINPROJ) ? w_in[((size_t)l * DINPROJ + r) * 256 + c] : 0.f;
        o_in[idx] = (f16)v;
    } else if (idx < N_CAST1 + N_CAST2) {
        int i = idx - N_CAST1;
        int k = i % DINNER;
        int l = i / (DMODEL * DINNER);
        o_out[i] = (f16)(w_out[i] * rmsw[l * DINNER + k]);
    } else if (idx < N_CAST1 + N_CAST2 + N_CAST3) {
        int i = idx - N_CAST1 - N_CAST2;
        o_c2[i] = (f16)w_c2[i];
    }
}

// ------- conv1 (3->64, k16, s4, pad6) + GELU -> f16, 8 outputs/thread -------
__global__ __launch_bounds__(256) void k_conv1(const float* __restrict__ x,
                                               const float* __restrict__ w,
                                               const float* __restrict__ bias,
                                               f16* __restrict__ out) {
    int idx = blockIdx.x * 256 + threadIdx.x;      // NB*64*256 = 131072
    int u  = idx & 255;                            // 8-output group
    int co = (idx >> 8) & 63;
    int b  = idx >> 14;
    int xbase = u * 32 - 8;

    float acc[8];
#pragma unroll
    for (int t = 0; t < 8; ++t) acc[t] = bias[co];

#pragma unroll
    for (int ci = 0; ci < 3; ++ci) {
        const float* xp = x + ((size_t)b * 3 + ci) * SEQ;
        float xb[48];
#pragma unroll
        for (int j = 0; j < 12; ++j) {
            int off = xbase + j * 4;
            float4 v;
            if (off >= 0 && off + 3 < SEQ) {
                v = *(const float4*)&xp[off];
            } else {
                v.x = (off + 0 >= 0 && off + 0 < SEQ) ? xp[off + 0] : 0.f;
                v.y = (off + 1 >= 0 && off + 1 < SEQ) ? xp[off + 1] : 0.f;
                v.z = (off + 2 >= 0 && off + 2 < SEQ) ? xp[off + 2] : 0.f;
                v.w = (off + 3 >= 0 && off + 3 < SEQ) ? xp[off + 3] : 0.f;
            }
            xb[j * 4 + 0] = v.x; xb[j * 4 + 1] = v.y;
            xb[j * 4 + 2] = v.z; xb[j * 4 + 3] = v.w;
        }
        const float* wp = w + (co * 3 + ci) * 16;
        float wv[16];
#pragma unroll
        for (int k = 0; k < 16; ++k) wv[k] = wp[k];
#pragma unroll
        for (int t = 0; t < 8; ++t)
#pragma unroll
            for (int k = 0; k < 16; ++k)
                acc[t] = fmaf(xb[t * 4 + k + 2], wv[k], acc[t]);
    }
    f16x8 o;
#pragma unroll
    for (int t = 0; t < 8; ++t) o[t] = (f16)gelu_f(acc[t]);
    *(f16x8*)&out[((size_t)(b * 64 + co)) * L1OUT + u * 8] = o;
}

// ------- im2col for conv2 (64ch, k16, s2, pad7), vectorized stores ----------
__global__ __launch_bounds__(256) void k_im2col(const f16* __restrict__ h1,
                                                f16* __restrict__ A) {
    int idx = blockIdx.x * 256 + threadIdx.x;      // 8192*128
    int g = idx & 127;
    int row = idx >> 7;
    int t = row & (LOUT - 1);
    int b = row >> 10;
    int ci = g >> 1, k0 = (g & 1) * 8;
    int pos0 = t * 2 + k0 - 7;
    const f16* hp = h1 + ((size_t)(b * 64 + ci)) * L1OUT;
    f16x8 v;
#pragma unroll
    for (int j = 0; j < 8; ++j) {
        int p = pos0 + j;
        v[j] = (p >= 0 && p < L1OUT) ? hp[p] : (f16)0.f;
    }
    *(f16x8*)&A[(size_t)row * 1024 + g * 8] = v;
}

// ---------------- fp16 MFMA GEMM: C[M,N] = A[M,K] * B[Npad,K]^T --------------
// BK=64, XOR-swizzled LDS, XCD-chunked block swizzle.
// EPI 1: gelu(v+bias); 2: f16 + dt cols -> dadt.
template<int BM, int EPI>
__global__ __launch_bounds__(256) void k_hgemm(const f16* __restrict__ A,
                                               const f16* __restrict__ Bw,
                                               f16* __restrict__ Ch,
                                               int M, int N, int K,
                                               const float* __restrict__ bias,
                                               const float* __restrict__ dt_bias,
                                               const float* __restrict__ A_log,
                                               float* __restrict__ dadt) {
    constexpr int MI = BM / 32;
    __shared__ f16 As[BM * 64];
    __shared__ f16 Bs[128 * 64];
    int tid  = threadIdx.x;
    int lane = tid & 63, wid = tid >> 6;
    int wm = wid >> 1, wn = wid & 1;

    int nbx = gridDim.x;
    int flat = blockIdx.y * nbx + blockIdx.x;
    int logical = xcd_chunk(flat, nbx * gridDim.y);
    int row0 = (logical / nbx) * BM, col0 = (logical % nbx) * 128;
    int lr = lane & 15, kb = lane >> 4;

    f32x4 acc[MI][4];
#pragma unroll
    for (int mi = 0; mi < MI; ++mi)
#pragma unroll
        for (int ni = 0; ni < 4; ++ni)
            acc[mi][ni] = (f32x4){0.f, 0.f, 0.f, 0.f};

    int sr  = tid >> 3;                         // 0..31 staging row
    int scx = ((tid & 7) ^ (sr & 7)) * 8;       // swizzled col (f16)
    int rsw = (lr & 7) * 8;                     // read-side XOR (f16)

    for (int k0 = 0; k0 < K; k0 += 64) {
        __syncthreads();
#pragma unroll
        for (int is = 0; is < BM / 32; ++is)
            gload16(A + (size_t)(row0 + is * 32 + sr) * K + k0 + scx,
                    &As[is * 2048 + wid * 512]);
#pragma unroll
        for (int is = 0; is < 4; ++is)
            gload16(Bw + (size_t)(col0 + is * 32 + sr) * K + k0 + scx,
                    &Bs[is * 2048 + wid * 512]);
        __syncthreads();

#pragma unroll
        for (int ks = 0; ks < 2; ++ks) {
            int cbase = (ks * 32 + kb * 8) ^ rsw;
            f16x8 a[MI], b[4];
#pragma unroll
            for (int mi = 0; mi < MI; ++mi)
                a[mi] = *reinterpret_cast<const f16x8*>(
                    &As[(wm * (BM / 2) + mi * 16 + lr) * 64 + cbase]);
#pragma unroll
            for (int ni = 0; ni < 4; ++ni)
                b[ni] = *reinterpret_cast<const f16x8*>(
                    &Bs[(wn * 64 + ni * 16 + lr) * 64 + cbase]);
#pragma unroll
            for (int mi = 0; mi < MI; ++mi)
#pragma unroll
                for (int ni = 0; ni < 4; ++ni)
                    acc[mi][ni] = __builtin_amdgcn_mfma_f32_16x16x32_f16(
                        a[mi], b[ni], acc[mi][ni], 0, 0, 0);
        }
    }

#pragma unroll
    for (int mi = 0; mi < MI; ++mi)
#pragma unroll
        for (int ni = 0; ni < 4; ++ni) {
            int ccol = col0 + wn * 64 + ni * 16 + lr;
            if (ccol < N) {
                int rbase = row0 + wm * (BM / 2) + mi * 16 + kb * 4;
                f32x4 v = acc[mi][ni];
#pragma unroll
                for (int r = 0; r < 4; ++r) {
                    float val = v[r];
                    if (EPI == 1) val = gelu_f(val + bias[ccol]);
                    Ch[(size_t)(rbase + r) * N + ccol] = (f16)val;
                    if (EPI == 2 && ccol >= DINNER + CONVDIM) {
                        int hh = ccol - (DINNER + CONVDIM);
                        float raw = val + dt_bias[hh];
                        float dtv = (raw > 20.f) ? raw : log1pf(__expf(raw));
                        float lda = -__expf(A_log[hh]) * dtv;
                        *(float2*)&dadt[(size_t)(rbase + r) * 32 + hh * 2] =
                            make_float2(lda, dtv);
                    }
                }
            }
        }
}

// ---------------- SSD part 1: per (b, chunk, 4 heads) ----------------
// Fused depthwise conv+SiLU staging of B/C/X from zx16; G = C.B^T;
// per head: S = X^T.(w*B)^T (f16), M = masked decay*G (+D on diag),
// Y_intra = M.X -> y1 (f16). hq==0 also writes conv'd C to C16 for ssd2.
__global__ __launch_bounds__(256) void k_ssd1(const f16* __restrict__ zx16,
                                              const float* __restrict__ dadt,
                                              const float* __restrict__ dw_w,
                                              const float* __restrict__ dw_b,
                                              const float* __restrict__ ssmD,
                                              f16* __restrict__ y1,
                                              f16* __restrict__ Sbuf16,
                                              float* __restrict__ Abuf,
                                              f16* __restrict__ C16) {
    __shared__ f16 Bs[64][72];
    __shared__ f16 Cs[64][72];
    __shared__ float GT[64][68];            // GT[s][t]
    __shared__ f16 Mw[4][64][72];           // X staging, then per-wave sBT / M
    __shared__ float2 LaDt[4][64];

    int tid = threadIdx.x, lane = tid & 63, wid = tid >> 6;
    int bid = xcd_chunk(blockIdx.x, NB * NCHUNK * 4);  // hq-blocks colocate
    int hq = bid & 3, c = (bid >> 2) & 15, b = bid >> 6;
    int h = hq * 4 + wid;
    int lr = lane & 15, kb = lane >> 4;
    f16* Xs = &Mw[0][0][0];                 // [64][260] f16 (33,280 B)

    // ---- fused conv+SiLU staging: threads 0..191 own (ch-group, 16-t slice)
    {
        int sg = tid % 48;                  // 0..31 X, 32..39 B, 40..47 C
        int ts = tid / 48;                  // t-slice (use 0..3)
        if (ts < 4) {
            int xc;                         // xbc-channel base (weight index)
            if (sg < 32)      xc = hq * 256 + sg * 8;
            else if (sg < 40) xc = 1024 + (sg - 32) * 8;
            else              xc = 1088 + (sg - 40) * 8;
            int zc = 1024 + xc;             // zx16 column
            float4 wv[8];
            float  bv[8];
#pragma unroll
            for (int j = 0; j < 8; ++j) {
                wv[j] = *(const float4*)&dw_w[(xc + j) * 4];
                bv[j] = dw_b[xc + j];
            }
            int l0 = c * 64 + ts * 16;      // in-batch row of first output
            const f16* zrow = zx16 + ((size_t)(b * 1024 + l0)) * DINPROJ + zc;
            f16x8 r0, r1, r2, r3;
            f16x8 zz;
#pragma unroll
            for (int j = 0; j < 8; ++j) zz[j] = (f16)0.f;
            r0 = (l0 >= 3) ? *(const f16x8*)(zrow - 3 * DINPROJ) : zz;
            r1 = (l0 >= 2) ? *(const f16x8*)(zrow - 2 * DINPROJ) : zz;
            r2 = (l0 >= 1) ? *(const f16x8*)(zrow - 1 * DINPROJ) : zz;
#pragma unroll
            for (int t = 0; t < 16; ++t) {
                r3 = *(const f16x8*)(zrow + t * DINPROJ);
                f16x8 o;
#pragma unroll
                for (int j = 0; j < 8; ++j) {
                    float s = bv[j];
                    s = fmaf((float)r0[j], wv[j].x, s);
                    s = fmaf((float)r1[j], wv[j].y, s);
                    s = fmaf((float)r2[j], wv[j].z, s);
                    s = fmaf((float)r3[j], wv[j].w, s);
                    o[j] = (f16)silu_f(s);
                }
                int row = ts * 16 + t;
                if (sg < 32) {
                    f16x4 o0 = {o[0], o[1], o[2], o[3]};
                    f16x4 o1 = {o[4], o[5], o[6], o[7]};
                    *(f16x4*)&Xs[row * 260 + sg * 8]     = o0;
                    *(f16x4*)&Xs[row * 260 + sg * 8 + 4] = o1;
                } else if (sg < 40) {
                    *(f16x8*)&Bs[row][(sg - 32) * 8] = o;
                } else {
                    *(f16x8*)&Cs[row][(sg - 40) * 8] = o;
                }
                r0 = r1; r1 = r2; r2 = r3;
            }
        }
    }

    // per-lane (lane = t): log-decay cumsum + dt (independent of staging)
    float2 ad = *(const float2*)&dadt[((size_t)(b * 1024 + c * 64 + lane) * 16 + h) * 2];
    float La = ad.x;
#pragma unroll
    for (int o = 1; o < 64; o <<= 1) {
        float v = __shfl_up(La, o);
        if (lane >= o) La += v;
    }
    float dt_own = ad.y;
    float La63 = __shfl(La, 63);
    float w_own = __expf(La63 - La) * dt_own;   // state weight, <= dt
    LaDt[wid][lane] = make_float2(La, dt_own);
    float Dh = ssmD[h];
    __syncthreads();

    // export conv'd C for ssd2 (one hq per (b,c))
    if (hq == 0) {
        f16* cp = C16 + (((size_t)(b * 16 + c)) << 12);
#pragma unroll
        for (int it = 0; it < 2; ++it) {
            int cid = it * 256 + tid;
            int row = cid >> 3, off = (cid & 7) * 8;
            *(f16x8*)&cp[row * 64 + off] = *(const f16x8*)&Cs[row][off];
        }
    }

    // read X^T fragments from LDS (row p, k=t)
    f16x8 xfrag[4][2];
#pragma unroll
    for (int pi = 0; pi < 4; ++pi)
#pragma unroll
        for (int ks = 0; ks < 2; ++ks) {
            f16x8 v;
#pragma unroll
            for (int j = 0; j < 8; ++j)
                v[j] = Xs[(ks * 32 + kb * 8 + j) * 260 + wid * 64 + pi * 16 + lr];
            xfrag[pi][ks] = v;
        }

    // G = C.B^T : each wave one 32x32 quadrant -> GT[s][t]
    {
        int tq = wid & 1, sq = wid >> 1;
        f32x4 g[2][2];
#pragma unroll
        for (int i = 0; i < 2; ++i)
#pragma unroll
            for (int j = 0; j < 2; ++j) g[i][j] = (f32x4){0.f, 0.f, 0.f, 0.f};
#pragma unroll
        for (int ks = 0; ks < 2; ++ks) {
            f16x8 a[2], bb[2];
#pragma unroll
            for (int ti = 0; ti < 2; ++ti)
                a[ti] = *(const f16x8*)&Cs[tq * 32 + ti * 16 + lr][ks * 32 + kb * 8];
#pragma unroll
            for (int si = 0; si < 2; ++si)
                bb[si] = *(const f16x8*)&Bs[sq * 32 + si * 16 + lr][ks * 32 + kb * 8];
#pragma unroll
            for (int ti = 0; ti < 2; ++ti)
#pragma unroll
                for (int si = 0; si < 2; ++si)
                    g[ti][si] = __builtin_amdgcn_mfma_f32_16x16x32_f16(
                        a[ti], bb[si], g[ti][si], 0, 0, 0);
        }
#pragma unroll
        for (int ti = 0; ti < 2; ++ti)
#pragma unroll
            for (int si = 0; si < 2; ++si)
#pragma unroll
                for (int r = 0; r < 4; ++r)
                    GT[sq * 32 + si * 16 + lr][tq * 32 + ti * 16 + kb * 4 + r] = g[ti][si][r];
    }
    __syncthreads();   // GT ready; all xfrag reads done -> Mw reusable

    // ---- head phase (wave-local) ----
    // sBT[n][t] = B[t][n] * w_t  into Mw[wid]
    {
        f16x8 brow[8];
#pragma unroll
        for (int i = 0; i < 8; ++i) brow[i] = *(const f16x8*)&Bs[lane][i * 8];
#pragma unroll
        for (int i = 0; i < 8; ++i)
#pragma unroll
            for (int j = 0; j < 8; ++j)
                Mw[wid][i * 8 + j][lane] = (f16)((float)brow[i][j] * w_own);
    }
    __builtin_amdgcn_wave_barrier();

    f16x8 sbfrag[4][2];
#pragma unroll
    for (int ni = 0; ni < 4; ++ni)
#pragma unroll
        for (int ks = 0; ks < 2; ++ks)
            sbfrag[ni][ks] = *(const f16x8*)&Mw[wid][ni * 16 + lr][ks * 32 + kb * 8];

    // S[p][n] = sum_t X^T[p][t] sBT[n][t]  -> f16
    {
        f32x4 accS[4][4];
#pragma unroll
        for (int pi = 0; pi < 4; ++pi)
#pragma unroll
            for (int ni = 0; ni < 4; ++ni) accS[pi][ni] = (f32x4){0.f, 0.f, 0.f, 0.f};
#pragma unroll
        for (int ks = 0; ks < 2; ++ks)
#pragma unroll
            for (int pi = 0; pi < 4; ++pi)
#pragma unroll
                for (int ni = 0; ni < 4; ++ni)
                    accS[pi][ni] = __builtin_amdgcn_mfma_f32_16x16x32_f16(
                        xfrag[pi][ks], sbfrag[ni][ks], accS[pi][ni], 0, 0, 0);
        size_t sbase = ((size_t)((b * 16 + h) * 16 + c)) << 12;
#pragma unroll
        for (int pi = 0; pi < 4; ++pi)
#pragma unroll
            for (int ni = 0; ni < 4; ++ni)
#pragma unroll
                for (int r = 0; r < 4; ++r)
                    Sbuf16[sbase + (size_t)(pi * 16 + kb * 4 + r) * 64 + ni * 16 + lr] =
                        (f16)accS[pi][ni][r];
        if (lane == 0) Abuf[(b * 16 + h) * 16 + c] = __expf(La63);
    }
    __builtin_amdgcn_wave_barrier();

    // M[t][s] = (s<=t) ? G[t][s]*exp(La_t-La_s)*dt_s : 0 ; M[t][t] += D_h
    {
        int t = lane;
        float la_t = La;
#pragma unroll
        for (int s8 = 0; s8 < 8; ++s8) {
            f16x8 mv;
#pragma unroll
            for (int j = 0; j < 8; ++j) {
                int s = s8 * 8 + j;
                float2 ld = LaDt[wid][s];
                float m = (s <= t) ? GT[s][t] * __expf(la_t - ld.x) * ld.y : 0.f;
                if (s == t) m += Dh;
                mv[j] = (f16)m;
            }
            *(f16x8*)&Mw[wid][t][s8 * 8] = mv;
        }
    }
    __builtin_amdgcn_wave_barrier();

    // Y_intra[t][p] = sum_s M[t][s] X[s][p]  -> f16 (includes D*xh)
    {
        f32x4 accY[4][4];
#pragma unroll
        for (int ti = 0; ti < 4; ++ti)
#pragma unroll
            for (int pi = 0; pi < 4; ++pi) accY[ti][pi] = (f32x4){0.f, 0.f, 0.f, 0.f};
#pragma unroll
        for (int ks = 0; ks < 2; ++ks) {
            f16x8 af[4];
#pragma unroll
            for (int ti = 0; ti < 4; ++ti)
                af[ti] = *(const f16x8*)&Mw[wid][ti * 16 + lr][ks * 32 + kb * 8];
#pragma unroll
            for (int ti = 0; ti < 4; ++ti)
#pragma unroll
                for (int pi = 0; pi < 4; ++pi)
                    accY[ti][pi] = __builtin_amdgcn_mfma_f32_16x16x32_f16(
                        af[ti], xfrag[pi][ks], accY[ti][pi], 0, 0, 0);
        }
        f16* yp = y1 + ((size_t)(b * 1024 + c * 64)) * 1024 + h * 64;
#pragma unroll
        for (int ti = 0; ti < 4; ++ti)
#pragma unroll
            for (int pi = 0; pi < 4; ++pi)
#pragma unroll
                for (int r = 0; r < 4; ++r)
                    yp[(size_t)(ti * 16 + kb * 4 + r) * 1024 + pi * 16 + lr] =
                        (f16)accY[ti][pi][r];
    }
}

// ------- fused inter-chunk recurrence + SSD part 2, 4-way p-split -----------
__global__ __launch_bounds__(256) void k_ssd2f(const f16* __restrict__ C16,
                                               const f16* __restrict__ Sbuf16,
                                               const float* __restrict__ Abuf,
                                               const float* __restrict__ dadt,
                                               f16* __restrict__ y2) {
    __shared__ f16 Hs[NCHUNK][1024];      // 32 KiB
    int tid = threadIdx.x, lane = tid & 63, wv = tid >> 6;
    int bid = xcd_chunk(blockIdx.x, NB * NHEADS * 4);   // same-b colocate
    int ph = bid & 3, h = (bid >> 2) & 15, b = bid >> 6;
    int bh = b * 16 + h;
    int lr = lane & 15, kb = lane >> 4;
    size_t base = ((size_t)bh << 16) + ph * 1024;   // p-slice offset in Sbuf

    // phase 1: recurrence for p in [ph*16, ph*16+16), 4 elems/thread
    {
        int lp = tid >> 4;                 // 0..15 local p
        int n0 = (tid & 15) * 4;           // 0..60
        int dst = lp * 64 + ((((n0 >> 3) ^ (lp & 7))) << 3) + (n0 & 7);
        float Hl[4];
#pragma unroll
        for (int j = 0; j < 4; ++j) Hl[j] = 0.f;
#pragma unroll
        for (int c = 0; c < NCHUNK; ++c) {
            f16x4 o;
#pragma unroll
            for (int j = 0; j < 4; ++j) o[j] = (f16)Hl[j];
            *(f16x4*)&Hs[c][dst] = o;
            float A = Abuf[bh * 16 + c];
            f16x4 s = *(const f16x4*)&Sbuf16[base + (size_t)c * 4096 + lp * 64 + n0];
#pragma unroll
            for (int j = 0; j < 4; ++j)
                Hl[j] = fmaf(Hl[j], A, (float)s[j]);
        }
    }
    __syncthreads();

    // phase 2
    const f16* cpb = C16 + ((size_t)b << 16);
#pragma unroll
    for (int i = 0; i < 4; ++i) {
        int c = wv * 4 + i;
        float2 ad = *(const float2*)&dadt[((size_t)(b * 1024 + c * 64 + lane) * 16 + h) * 2];
        float La = ad.x;
#pragma unroll
        for (int o = 1; o < 64; o <<= 1) {
            float v = __shfl_up(La, o);
            if (lane >= o) La += v;
        }

        f16x8 hfrag[2];
#pragma unroll
        for (int ks = 0; ks < 2; ++ks) {
            int cf = (ks * 32 + kb * 8) ^ ((lr & 7) * 8);
            hfrag[ks] = *(const f16x8*)&Hs[c][lr * 64 + cf];
        }

        const f16* cp = cpb + ((size_t)c << 12);
        f32x4 acc[4];
#pragma unroll
        for (int ti = 0; ti < 4; ++ti) acc[ti] = (f32x4){0.f, 0.f, 0.f, 0.f};
#pragma unroll
        for (int ks = 0; ks < 2; ++ks) {
            f16x8 af[4];
#pragma unroll
            for (int ti = 0; ti < 4; ++ti)
                af[ti] = *(const f16x8*)(cp + (ti * 16 + lr) * 64 + ks * 32 + kb * 8);
#pragma unroll
            for (int ti = 0; ti < 4; ++ti)
                acc[ti] = __builtin_amdgcn_mfma_f32_16x16x32_f16(
                    af[ti], hfrag[ks], acc[ti], 0, 0, 0);
        }
        f16* yp = y2 + ((size_t)(b * 1024 + c * 64)) * 1024 + h * 64 + ph * 16;
#pragma unroll
        for (int ti = 0; ti < 4; ++ti)
#pragma unroll
            for (int r = 0; r < 4; ++r) {
                int t = ti * 16 + kb * 4 + r;
                float sc = __expf(__shfl(La, t));
                yp[(size_t)t * 1024 + lr] = (f16)(sc * acc[ti][r]);
            }
    }
}

// --- fused gate + RMSNorm + out_proj v2: gate in REGISTERS, single N pass ---
// Block = 32 rows x 256 cols, 256 threads, xcd_chunk swizzle.
// W' = Wout * rmsw (premultiplied). out = (r*(y1+y2)*silu(z)) @ W'^T.
__global__ __launch_bounds__(256) void k_goproj(const f16* __restrict__ y1,
                                                const f16* __restrict__ y2,
                                                const f16* __restrict__ zx16,
                                                const f16* __restrict__ Bw,
                                                f16* __restrict__ out) {
    __shared__ f16 Bs[256 * 64];     // 32 KiB per k-chunk
    __shared__ f16 Ag[32 * 64];      // 4 KiB gated A chunk
    int tid = threadIdx.x, lane = tid & 63, wv = tid >> 6;
    int row0 = xcd_chunk(blockIdx.x, 256) * 32;
    int lr = lane & 15, kb = lane >> 4;
    int row = tid >> 3, seg = tid & 7;

    // pass 1: gate values -> registers; per-row sum of squares
    f16x8 vreg[16];
    float ss = 0.f;
    {
        const f16* p1 = y1 + (size_t)(row0 + row) * DINNER;
        const f16* p2 = y2 + (size_t)(row0 + row) * DINNER;
        const f16* pz = zx16 + (size_t)(row0 + row) * DINPROJ;
#pragma unroll
        for (int kc = 0; kc < 16; ++kc) {
            int c = kc * 64 + seg * 8;
            f16x8 a = *(const f16x8*)(p1 + c);
            f16x8 b = *(const f16x8*)(p2 + c);
            f16x8 z = *(const f16x8*)(pz + c);
            f16x8 o;
#pragma unroll
            for (int j = 0; j < 8; ++j) {
                float v = ((float)a[j] + (float)b[j]) * silu_f((float)z[j]);
                ss += v * v;
                o[j] = (f16)v;
            }
            vreg[kc] = o;
        }
        ss += __shfl_xor(ss, 1);
        ss += __shfl_xor(ss, 2);
        ss += __shfl_xor(ss, 4);
    }
    float rnorm = rsqrtf(ss * (1.f / DINNER) + 1e-5f);

    int sr  = tid >> 3;                         // 0..31 staging row
    int scx = ((tid & 7) ^ (sr & 7)) * 8;
    int rsw = (lr & 7) * 8;
    int agw = (seg ^ (row & 7)) * 8;

    f32x4 acc[2][4];
#pragma unroll
    for (int mi = 0; mi < 2; ++mi)
#pragma unroll
        for (int ni = 0; ni < 4; ++ni)
            acc[mi][ni] = (f32x4){0.f, 0.f, 0.f, 0.f};

#pragma unroll
    for (int kc = 0; kc < 16; ++kc) {
        int k0 = kc * 64;
        __syncthreads();
#pragma unroll
        for (int is = 0; is < 8; ++is)
            gload16(Bw + (size_t)(is * 32 + sr) * DINNER + k0 + scx,
                    &Bs[is * 2048 + wv * 512]);
        {
            f16x8 o;
#pragma unroll
            for (int j = 0; j < 8; ++j)
                o[j] = (f16)((float)vreg[kc][j] * rnorm);
            *(f16x8*)&Ag[row * 64 + agw] = o;
        }
        __syncthreads();

#pragma unroll
        for (int ks = 0; ks < 2; ++ks) {
            int cb = (ks * 32 + kb * 8) ^ rsw;
            f16x8 a0 = *(const f16x8*)&Ag[lr * 64 + cb];
            f16x8 a1 = *(const f16x8*)&Ag[(16 + lr) * 64 + cb];
            f16x8 bfr[4];
#pragma unroll
            for (int ni = 0; ni < 4; ++ni)
                bfr[ni] = *(const f16x8*)&Bs[(wv * 64 + ni * 16 + lr) * 64 + cb];
#pragma unroll
            for (int ni = 0; ni < 4; ++ni) {
                acc[0][ni] = __builtin_amdgcn_mfma_f32_16x16x32_f16(
                    a0, bfr[ni], acc[0][ni], 0, 0, 0);
                acc[1][ni] = __builtin_amdgcn_mfma_f32_16x16x32_f16(
                    a1, bfr[ni], acc[1][ni], 0, 0, 0);
            }
        }
    }

#pragma unroll
    for (int mi = 0; mi < 2; ++mi)
#pragma unroll
        for (int ni = 0; ni < 4; ++ni) {
            int ccol = wv * 64 + ni * 16 + lr;
#pragma unroll
            for (int r = 0; r < 4; ++r)
                out[(size_t)(row0 + mi * 16 + kb * 4 + r) * DMODEL + ccol] =
                    (f16)acc[mi][ni][r];
        }
}

// -- final LayerNorm + mean pool: wave-per-row, per-(b,seg) partial (no atomic)
__global__ __launch_bounds__(256) void k_lnpool(const f16* __restrict__ h,
                                                const float* __restrict__ lnw,
                                                const float* __restrict__ lnb,
                                                float* __restrict__ pooledp) {
    __shared__ float pl[4][256];
    int bid = blockIdx.x;                // 8 * 32
    int b = bid >> 5, seg = bid & 31;
    int tid = threadIdx.x, lane = tid & 63, w = tid >> 6;
    int c4 = lane * 4;
    float4 lw = *(const float4*)&lnw[c4];
    float4 lb = *(const float4*)&lnb[c4];
    float acc0 = 0.f, acc1 = 0.f, acc2 = 0.f, acc3 = 0.f;
    const f16* hb = h + ((size_t)b * 1024 + seg * 32 + w * 8) * DMODEL;
#pragma unroll
    for (int i = 0; i < 8; ++i) {
        f16x4 hv = *(const f16x4*)(hb + (size_t)i * DMODEL + c4);
        float vx = (float)hv.x, vy = (float)hv.y, vz = (float)hv.z, vw = (float)hv.w;
        float s1 = vx + vy + vz + vw;
        float s2 = vx * vx + vy * vy + vz * vz + vw * vw;
#pragma unroll
        for (int o = 32; o > 0; o >>= 1) {
            s1 += __shfl_xor(s1, o);
            s2 += __shfl_xor(s2, o);
        }
        float mu = s1 * (1.f / DMODEL);
        float var = s2 * (1.f / DMODEL) - mu * mu;
        float rr = rsqrtf(var + 1e-5f);
        acc0 += (vx - mu) * rr * lw.x + lb.x;
        acc1 += (vy - mu) * rr * lw.y + lb.y;
        acc2 += (vz - mu) * rr * lw.z + lb.z;
        acc3 += (vw - mu) * rr * lw.w + lb.w;
    }
    pl[w][c4 + 0] = acc0; pl[w][c4 + 1] = acc1;
    pl[w][c4 + 2] = acc2; pl[w][c4 + 3] = acc3;
    __syncthreads();
    float tot = pl[0][tid] + pl[1][tid] + pl[2][tid] + pl[3][tid];
    pooledp[(size_t)(b * 32 + seg) * 256 + tid] = tot;
}

// ---------------- regression head (reduces 32 partials) ----------------
__global__ __launch_bounds__(128) void k_head(const float* __restrict__ pooledp,
                                              const float* __restrict__ w1,
                                              const float* __restrict__ b1,
                                              const float* __restrict__ w2,
                                              const float* __restrict__ b2,
                                              float* __restrict__ out) {
    __shared__ float sp[256];
    __shared__ float red[2];
    int b = blockIdx.x, j = threadIdx.x;
    for (int d = j; d < 256; d += 128) {
        float s = 0.f;
#pragma unroll
        for (int seg = 0; seg < 32; ++seg)
            s += pooledp[(size_t)(b * 32 + seg) * 256 + d];
        sp[d] = s * (1.f / LOUT);
    }
    __syncthreads();
    float acc = b1[j];
#pragma unroll 8
    for (int d = 0; d < DMODEL; ++d)
        acc = fmaf(sp[d], w1[j * DMODEL + d], acc);
    float r = gelu_f(acc) * w2[j];
#pragma unroll
    for (int o = 32; o > 0; o >>= 1) r += __shfl_down(r, o, 64);
    int lane = j & 63, wid = j >> 6;
    if (lane == 0) red[wid] = r;
    __syncthreads();
    if (j == 0) out[b] = red[0] + red[1] + b2[0];
}

extern "C" void kernel_launch(void* const* d_in, const int* in_sizes, int n_in,
                              void* d_out, int out_size, void* d_ws, size_t ws_size,
                              hipStream_t stream) {
    const float* x         = (const float*)d_in[0];
    const float* conv1_w   = (const float*)d_in[1];
    const float* conv1_b   = (const float*)d_in[2];
    const float* conv2_w   = (const float*)d_in[3];
    const float* conv2_b   = (const float*)d_in[4];
    const float* in_proj_w = (const float*)d_in[5];
    const float* dw_w      = (const float*)d_in[6];
    const float* dw_b      = (const float*)d_in[7];
    const float* dt_bias   = (const float*)d_in[8];
    const float* A_log     = (const float*)d_in[9];
    const float* ssm_D     = (const float*)d_in[10];
    const float* rms_w     = (const float*)d_in[11];
    const float* out_proj_w= (const float*)d_in[12];
    const float* ln_w      = (const float*)d_in[13];
    const float* ln_b      = (const float*)d_in[14];
    const float* reg1_w    = (const float*)d_in[15];
    const float* reg1_b    = (const float*)d_in[16];
    const float* reg2_w    = (const float*)d_in[17];
    const float* reg2_b    = (const float*)d_in[18];

    float* ws = (float*)d_ws;
    size_t off = 0;
    float* dadt    = ws + off; off += (size_t)NB * LOUT * NHEADS * 2; // 262,144
    float* Abuf    = ws + off; off += (size_t)NB * NHEADS * NCHUNK;   // 2,048
    float* pooledp = ws + off; off += (size_t)NB * 32 * 256;          // 65,536

    f16* fbase = (f16*)(ws + off);
    size_t foff = 0;
    f16* c1f16  = fbase + foff; foff += (size_t)NB * 64 * L1OUT;
    f16* hbf0   = fbase + foff; foff += (size_t)NB * LOUT * DMODEL;
    f16* hbf1   = fbase + foff; foff += (size_t)NB * LOUT * DMODEL;
    f16* y2     = fbase + foff; foff += (size_t)NB * LOUT * DINNER;
    f16* y1     = fbase + foff; foff += (size_t)NB * LOUT * DINNER;   // also im2h
    f16* C16    = fbase + foff; foff += (size_t)NB * NCHUNK * 64 * 64;
    f16* zx16   = fbase + foff; foff += (size_t)NB * LOUT * DINPROJ;
    f16* Sbuf16 = fbase + foff; foff += (size_t)NB * NHEADS * NCHUNK * 4096;
    f16* w_in_h = fbase + foff; foff += (size_t)NLAYERS * NPADIN * DMODEL;
    f16* w_out_h= fbase + foff; foff += (size_t)NLAYERS * DMODEL * DINNER;
    f16* w_c2_h = fbase + foff; foff += (size_t)DMODEL * 1024;
    f16* im2h   = y1;          // aliased: im2col dead before y1 first written

    // all weight casts (out_proj premultiplied by rms_w)
    {
        int total = N_CAST1 + N_CAST2 + N_CAST3;
        k_castall<<<(total + 255) / 256, 256, 0, stream>>>(
            in_proj_w, out_proj_w, rms_w, conv2_w, w_in_h, w_out_h, w_c2_h);
    }

    // front-end convs
    k_conv1<<<(NB * 64 * 256) / 256, 256, 0, stream>>>(x, conv1_w, conv1_b, c1f16);
    k_im2col<<<(NB * LOUT * 128) / 256, 256, 0, stream>>>(c1f16, im2h);
    {
        dim3 g(256 / 128, 8192 / 64);
        k_hgemm<64, 1><<<g, 256, 0, stream>>>(im2h, w_c2_h, hbf0,
                                              8192, 256, 1024, conv2_b,
                                              nullptr, nullptr, nullptr);
    }

    f16* hcur = hbf0;
    f16* hnxt = hbf1;
    for (int i = 0; i < NLAYERS; ++i) {
        {
            dim3 g(NPADIN / 128, 8192 / 128);
            k_hgemm<128, 2><<<g, 256, 0, stream>>>(
                hcur, w_in_h + (size_t)i * NPADIN * DMODEL, zx16,
                8192, DINPROJ, DMODEL, nullptr,
                dt_bias + i * NHEADS, A_log + i * NHEADS, dadt);
        }
        k_ssd1<<<NB * NCHUNK * 4, 256, 0, stream>>>(
            zx16, dadt, dw_w + (size_t)i * CONVDIM * 4, dw_b + (size_t)i * CONVDIM,
            ssm_D + i * NHEADS, y1, Sbuf16, Abuf, C16);
        k_ssd2f<<<NB * NHEADS * 4, 256, 0, stream>>>(C16, Sbuf16, Abuf, dadt, y2);
        k_goproj<<<8192 / 32, 256, 0, stream>>>(
            y1, y2, zx16, w_out_h + (size_t)i * DMODEL * DINNER, hnxt);
        f16* tmp = hcur; hcur = hnxt; hnxt = tmp;
    }

    // final LN + pool + head
    k_lnpool<<<NB * 32, 256, 0, stream>>>(hcur, ln_w, ln_b, pooledp);
    k_head<<<NB, 128, 0, stream>>>(pooledp, reg1_w, reg1_b, reg2_w, reg2_b, (float*)d_out);
}